// Round 4
// baseline (729.252 us; speedup 1.0000x reference)
//
#include <hip/hip_runtime.h>
#include <math.h>

#define NB    64        // graphs
#define NPER  1024      // nodes per graph
#define NTOT  65536     // total nodes
#define ETOT  1048576   // edges
#define FEAT  64
#define HID   128
#define KSEL  10
#define MAXDEG 64       // CSR slot capacity per node (max in-degree ~40)
#define NCH   8         // feature chunks of 16

// Layouts:
//   Y / P / Q : chunk-major  CY[c][v][16]  — one node's chunk row = one 64B line
//   col / iw  : slot-major   col[i][v]     — slot i for consecutive v is contiguous

// ---------------- CSR build (slot-major) ----------------
__global__ __launch_bounds__(256) void csr_k(const int* __restrict__ src,
                                             const int* __restrict__ dst,
                                             int* __restrict__ cnt,
                                             int* __restrict__ col) {
    int e = blockIdx.x * 256 + threadIdx.x;
    if (e >= ETOT) return;
    int d = dst[e];
    int s = src[e];
    int pos = atomicAdd(&cnt[d], 1);
    col[(size_t)pos * NTOT + d] = s;
}

__global__ __launch_bounds__(256) void dinv_k(const int* __restrict__ cnt,
                                              float* __restrict__ dinv) {
    int v = blockIdx.x * 256 + threadIdx.x;
    if (v >= NTOT) return;
    dinv[v] = rsqrtf((float)cnt[v] + 1.0f);
}

// pack (src, norm weight) per slot, slot-major
__global__ __launch_bounds__(256) void wgt_k(const int* __restrict__ col,
                                             const int* __restrict__ cnt,
                                             const float* __restrict__ dinv,
                                             int2* __restrict__ iw) {
    int idx = blockIdx.x * 256 + threadIdx.x;   // = i*NTOT + v
    int v = idx & (NTOT - 1);
    int i = idx >> 16;
    if (i >= cnt[v]) return;
    int s = col[idx];
    iw[idx] = make_int2(s, __float_as_int(dinv[s] * dinv[v]));
}

// ---------------- fp32 GEMM: Y = A @ W (+ per-graph gproj), Y chunk-major ---------
__global__ __launch_bounds__(256) void gemm_k(const float* __restrict__ A,
                                              const float* __restrict__ W,
                                              float* __restrict__ Y,
                                              const float* __restrict__ gproj,
                                              int K, int chunkedA) {
    __shared__ float At[32][68];
    __shared__ float Wt[32][128];
    int t = threadIdx.x;
    int row0 = blockIdx.x * 64;
    int tx = t & 31;
    int ty = t >> 5;

    float acc[8][4];
#pragma unroll
    for (int i = 0; i < 8; ++i)
#pragma unroll
        for (int j = 0; j < 4; ++j) acc[i][j] = 0.f;

    for (int kt = 0; kt < K; kt += 32) {
        {
            int r = t >> 5;
            int k = t & 31;
            int kk = kt + k;
#pragma unroll
            for (int rr = 0; rr < 8; ++rr) {
                int row = row0 + r + rr * 8;
                float val;
                if (chunkedA)
                    val = A[((size_t)(kk >> 4) * NTOT + row) * 16 + (kk & 15)];
                else
                    val = A[(size_t)row * K + kk];
                At[k][r + rr * 8] = val;
            }
        }
        {
            int c = t & 127;
            int kr = t >> 7;
#pragma unroll
            for (int kk = 0; kk < 16; ++kk)
                Wt[kr + kk * 2][c] = W[(size_t)(kt + kr + kk * 2) * 128 + c];
        }
        __syncthreads();
#pragma unroll
        for (int k = 0; k < 32; ++k) {
            float4 a0 = *(const float4*)&At[k][ty * 8];
            float4 a1 = *(const float4*)&At[k][ty * 8 + 4];
            float4 w  = *(const float4*)&Wt[k][tx * 4];
            float a[8] = {a0.x, a0.y, a0.z, a0.w, a1.x, a1.y, a1.z, a1.w};
#pragma unroll
            for (int i = 0; i < 8; ++i) {
                acc[i][0] += a[i] * w.x;
                acc[i][1] += a[i] * w.y;
                acc[i][2] += a[i] * w.z;
                acc[i][3] += a[i] * w.w;
            }
        }
        __syncthreads();
    }

    float4 g4 = make_float4(0.f, 0.f, 0.f, 0.f);
    if (gproj) {
        int g = row0 >> 10;
        g4 = *(const float4*)&gproj[(size_t)g * 128 + tx * 4];
    }
    int cc = tx >> 2;            // feature chunk
    int co = (tx & 3) * 4;       // offset within chunk
#pragma unroll
    for (int i = 0; i < 8; ++i) {
        int r = row0 + ty * 8 + i;
        float4 o;
        o.x = acc[i][0] + g4.x;
        o.y = acc[i][1] + g4.y;
        o.z = acc[i][2] + g4.z;
        o.w = acc[i][3] + g4.w;
        *(float4*)&Y[((size_t)cc * NTOT + r) * 16 + co] = o;
    }
}

// ---------------- direct-gather GCN aggregation -----------------------------------
// 1024 blocks x 256 threads, no LDS staging. 4 threads per node; thread q owns
// float4 slot q of each of the 8 chunks (32 features). Edges read ONCE total.
// Graph's 16 blocks share blockIdx%8 -> same XCD L2 (holds the 512KB Y slice).
__global__ __launch_bounds__(256) void gagg_k(const float* __restrict__ Y,
                                              const int2* __restrict__ iw,
                                              const int* __restrict__ cnt,
                                              const float* __restrict__ dinv,
                                              const float* __restrict__ bias,
                                              float* __restrict__ out,
                                              float* __restrict__ lin3,
                                              const float* __restrict__ W3,
                                              float* __restrict__ part) {
    int b = blockIdx.x;
    int g = b & 63;              // graph; XCD = b%8 = g%8 for all 16 sub-blocks
    int sub = b >> 6;            // 0..15
    int t = threadIdx.x;
    int q = t & 3;               // float4 slot within chunk
    int l = t >> 2;              // 0..63 local node
    int v = (g << 10) + (sub << 6) + l;

    float dv = dinv[v];
    int n = cnt[v];
    float dvv = dv * dv;
    const float* Yq = Y + q * 4;

    float4 acc[8];
#pragma unroll
    for (int c = 0; c < 8; ++c) {
        float4 s = *(const float4*)(Yq + ((size_t)c * NTOT + v) * 16);
        acc[c].x = s.x * dvv; acc[c].y = s.y * dvv;
        acc[c].z = s.z * dvv; acc[c].w = s.w * dvv;
    }

    const int2* ip = iw + v;
    int i = 0;
    for (; i + 2 <= n; i += 2) {
        int2 ea = ip[(size_t)i * NTOT];
        int2 eb = ip[(size_t)(i + 1) * NTOT];
        float wa = __int_as_float(ea.y), wb = __int_as_float(eb.y);
        const float* pa = Yq + (size_t)ea.x * 16;
        const float* pb = Yq + (size_t)eb.x * 16;
#pragma unroll
        for (int c = 0; c < 8; ++c) {
            float4 ya = *(const float4*)(pa + (size_t)c * NTOT * 16);
            float4 yb = *(const float4*)(pb + (size_t)c * NTOT * 16);
            acc[c].x += ya.x * wa + yb.x * wb;
            acc[c].y += ya.y * wa + yb.y * wb;
            acc[c].z += ya.z * wa + yb.z * wb;
            acc[c].w += ya.w * wa + yb.w * wb;
        }
    }
    if (i < n) {
        int2 e = ip[(size_t)i * NTOT];
        float w = __int_as_float(e.y);
        const float* p = Yq + (size_t)e.x * 16;
#pragma unroll
        for (int c = 0; c < 8; ++c) {
            float4 y = *(const float4*)(p + (size_t)c * NTOT * 16);
            acc[c].x += y.x * w; acc[c].y += y.y * w;
            acc[c].z += y.z * w; acc[c].w += y.w * w;
        }
    }

#pragma unroll
    for (int c = 0; c < 8; ++c) {
        float4 bb = *(const float4*)(bias + c * 16 + q * 4);
        acc[c].x = fmaxf(acc[c].x + bb.x, 0.f);
        acc[c].y = fmaxf(acc[c].y + bb.y, 0.f);
        acc[c].z = fmaxf(acc[c].z + bb.z, 0.f);
        acc[c].w = fmaxf(acc[c].w + bb.w, 0.f);
    }

    if (out) {
#pragma unroll
        for (int c = 0; c < 8; ++c)
            *(float4*)(out + ((size_t)c * NTOT + v) * 16 + q * 4) = acc[c];
    }

    if (W3) {   // lin3[v] = dot(relu row, W3) via quad reduce
        float p = 0.f;
#pragma unroll
        for (int c = 0; c < 8; ++c) {
            float4 w4 = *(const float4*)(W3 + c * 16 + q * 4);
            p += acc[c].x * w4.x + acc[c].y * w4.y + acc[c].z * w4.z + acc[c].w * w4.w;
        }
        p += __shfl_xor(p, 1);
        p += __shfl_xor(p, 2);
        if (q == 0) lin3[v] = p;
    }

    if (part) {  // per-graph feature max: block-reduce 64 nodes, then atomicMax (relu>=0)
        __shared__ float4 sm[256];
#pragma unroll 1
        for (int c = 0; c < 8; ++c) {
            sm[t] = acc[c];
            __syncthreads();
            for (int s = 32; s >= 1; s >>= 1) {
                if (l < s) {
                    float4 a = sm[l * 4 + q], b2 = sm[(l + s) * 4 + q];
                    a.x = fmaxf(a.x, b2.x); a.y = fmaxf(a.y, b2.y);
                    a.z = fmaxf(a.z, b2.z); a.w = fmaxf(a.w, b2.w);
                    sm[l * 4 + q] = a;
                }
                __syncthreads();
            }
            if (l == 0) {
                int* pp = (int*)(part + (size_t)g * 128 + c * 16 + q * 4);
                float4 m = sm[q];
                atomicMax(pp + 0, __float_as_int(m.x));
                atomicMax(pp + 1, __float_as_int(m.y));
                atomicMax(pp + 2, __float_as_int(m.z));
                atomicMax(pp + 3, __float_as_int(m.w));
            }
            __syncthreads();
        }
    }
}

// ---------------- glob = maxpool@Wf + bf ; gproj = glob @ W2[128:256,:] --------------
__global__ __launch_bounds__(128) void glob_k(const float* __restrict__ part,
                                              const float* __restrict__ Wf,
                                              const float* __restrict__ bf,
                                              const float* __restrict__ W2,
                                              float* __restrict__ gproj) {
    __shared__ float mp[128];
    __shared__ float gl[128];
    int g = blockIdx.x, t = threadIdx.x;
    mp[t] = part[(size_t)g * 128 + t];
    __syncthreads();
    float acc = bf[t];
    for (int k = 0; k < 128; ++k) acc += mp[k] * Wf[(size_t)k * 128 + t];
    gl[t] = acc;
    __syncthreads();
    float acc2 = 0.f;
    for (int k = 0; k < 128; ++k) acc2 += gl[k] * W2[(size_t)(128 + k) * 128 + t];
    gproj[(size_t)g * 128 + t] = acc2;
}

// ---------------- scalar aggregation for logits (slot-major edges) -------------------
__global__ __launch_bounds__(256) void sagg_k(const float* __restrict__ lin3,
                                              const int2* __restrict__ iw,
                                              const int* __restrict__ cnt,
                                              const float* __restrict__ dinv,
                                              const float* __restrict__ b3,
                                              float* __restrict__ logits) {
    int v = blockIdx.x * 256 + threadIdx.x;
    if (v >= NTOT) return;
    float dv = dinv[v];
    float acc = lin3[v] * dv * dv;
    int n = cnt[v];
    const int2* ip = iw + v;
    int i = 0;
    for (; i + 2 <= n; i += 2) {
        int2 e0 = ip[(size_t)(i + 0) * NTOT];
        int2 e1 = ip[(size_t)(i + 1) * NTOT];
        acc += lin3[e0.x] * __int_as_float(e0.y) + lin3[e1.x] * __int_as_float(e1.y);
    }
    for (; i < n; ++i) {
        int2 e = ip[(size_t)i * NTOT];
        acc += lin3[e.x] * __int_as_float(e.y);
    }
    logits[v] = acc + b3[0];
}

// ---------------- per-graph top-K threshold + mask -----------------------------------
__global__ __launch_bounds__(256) void mask_k(const float* __restrict__ logits,
                                              float* __restrict__ out) {
    __shared__ float sl[1024];
    __shared__ float rv[256];
    __shared__ int   ri[256];
    __shared__ float sth;
    int g = blockIdx.x, t = threadIdx.x;
    const float* lg = logits + (size_t)g * 1024;
#pragma unroll
    for (int i = 0; i < 4; ++i) sl[t + 256 * i] = lg[t + 256 * i];
    __syncthreads();
    for (int pass = 0; pass < KSEL; ++pass) {
        float bv = -INFINITY;
        int bi = 0;
#pragma unroll
        for (int i = 0; i < 4; ++i) {
            float v = sl[t + 256 * i];
            if (v > bv) { bv = v; bi = t + 256 * i; }
        }
        rv[t] = bv; ri[t] = bi;
        __syncthreads();
        for (int s = 128; s > 0; s >>= 1) {
            if (t < s) {
                if (rv[t + s] > rv[t]) { rv[t] = rv[t + s]; ri[t] = ri[t + s]; }
            }
            __syncthreads();
        }
        if (t == 0) { sth = rv[0]; sl[ri[0]] = -INFINITY; }
        __syncthreads();
    }
    float th = sth;
#pragma unroll
    for (int i = 0; i < 4; ++i) {
        float v = lg[t + 256 * i];
        out[(size_t)g * 1024 + t + 256 * i] = (v >= th) ? 1.f : 0.f;
    }
}

// =====================================================================================
extern "C" void kernel_launch(void* const* d_in, const int* in_sizes, int n_in,
                              void* d_out, int out_size, void* d_ws, size_t ws_size,
                              hipStream_t stream) {
    const float* x        = (const float*)d_in[0];
    const int*   edge_src = (const int*)d_in[1];
    const int*   edge_dst = (const int*)d_in[2];
    const float* W0 = (const float*)d_in[4];
    const float* b0 = (const float*)d_in[5];
    const float* W1 = (const float*)d_in[6];
    const float* b1 = (const float*)d_in[7];
    const float* Wf = (const float*)d_in[8];
    const float* bf = (const float*)d_in[9];
    const float* W2 = (const float*)d_in[10];
    const float* b2 = (const float*)d_in[11];
    const float* W3 = (const float*)d_in[12];
    const float* b3 = (const float*)d_in[13];
    float* out = (float*)d_out;

    char* w = (char*)d_ws;
    int*   cnt    = (int*)w;   w += (size_t)NTOT * 4;
    float* dinv   = (float*)w; w += (size_t)NTOT * 4;
    int*   col    = (int*)w;   w += (size_t)NTOT * MAXDEG * 4;
    int2*  iw     = (int2*)w;  w += (size_t)NTOT * MAXDEG * 8;
    float* P      = (float*)w; w += (size_t)NTOT * 128 * 4;
    float* Q      = (float*)w; w += (size_t)NTOT * 128 * 4;
    float* part   = (float*)w; w += (size_t)NB * 128 * 4;
    float* gproj  = (float*)w; w += (size_t)NB * 128 * 4;
    float* lin3   = (float*)w; w += (size_t)NTOT * 4;
    float* logits = (float*)w; w += (size_t)NTOT * 4;

    hipMemsetAsync(cnt, 0, (size_t)NTOT * 4, stream);
    hipMemsetAsync(part, 0, (size_t)NB * 128 * 4, stream);   // atomicMax base (relu>=0)
    csr_k<<<ETOT / 256, 256, 0, stream>>>(edge_src, edge_dst, cnt, col);
    dinv_k<<<NTOT / 256, 256, 0, stream>>>(cnt, dinv);
    wgt_k<<<NTOT * MAXDEG / 256, 256, 0, stream>>>(col, cnt, dinv, iw);

    // conv0: Q = relu(agg(x@W0)+b0); fused per-graph max -> part (atomicMax)
    gemm_k<<<NTOT / 64, 256, 0, stream>>>(x, W0, P, nullptr, FEAT, 0);
    gagg_k<<<1024, 256, 0, stream>>>(P, iw, cnt, dinv, b0, Q, nullptr, nullptr, part);

    glob_k<<<NB, 128, 0, stream>>>(part, Wf, bf, W2, gproj);

    // conv1 twice (same weights), ping-pong Q->P->Q
    gemm_k<<<NTOT / 64, 256, 0, stream>>>(Q, W1, P, nullptr, HID, 1);
    gagg_k<<<1024, 256, 0, stream>>>(P, iw, cnt, dinv, b1, Q, nullptr, nullptr, nullptr);
    gemm_k<<<NTOT / 64, 256, 0, stream>>>(Q, W1, P, nullptr, HID, 1);
    gagg_k<<<1024, 256, 0, stream>>>(P, iw, cnt, dinv, b1, Q, nullptr, nullptr, nullptr);

    // conv2 on concat (gproj added in gemm epilogue); fused lin3 = relu(out)@W3
    gemm_k<<<NTOT / 64, 256, 0, stream>>>(Q, W2, P, gproj, HID, 1);
    gagg_k<<<1024, 256, 0, stream>>>(P, iw, cnt, dinv, b2, nullptr, lin3, W3, nullptr);

    sagg_k<<<NTOT / 256, 256, 0, stream>>>(lin3, iw, cnt, dinv, b3, logits);
    mask_k<<<NB, 256, 0, stream>>>(logits, out);
}

// Round 5
// 364.255 us; speedup vs baseline: 2.0020x; 2.0020x over previous
//
#include <hip/hip_runtime.h>
#include <math.h>

#define NB    64        // graphs
#define NPER  1024      // nodes per graph
#define NTOT  65536     // total nodes
#define ETOT  1048576   // edges
#define FEAT  64
#define HID   128
#define KSEL  10
#define MAXDEG 64       // CSR slot capacity per node (max in-degree ~40)
#define NCH   8         // feature chunks of 16

// Layouts:
//   Z / h buffers : chunk-major  C[c][v][16]  (c = feature chunk of 16 floats)
//   col16         : slot-major   col16[i][v]  = LOCAL (10-bit) neighbor index, u16
// Norm factored as Z = dinv*Y in gemm epilogue  ->  agg needs NO per-edge weight:
//   h_v = relu( dinv_v * (Z_v + sum_{s in N(v)} Z_s) + bias )

// ---------------- CSR build (slot-major, u16 local index) ----------------
__global__ __launch_bounds__(256) void csr_k(const int* __restrict__ src,
                                             const int* __restrict__ dst,
                                             int* __restrict__ cnt,
                                             unsigned short* __restrict__ col16) {
    int e = blockIdx.x * 256 + threadIdx.x;
    if (e >= ETOT) return;
    int d = dst[e];
    int s = src[e];
    int pos = atomicAdd(&cnt[d], 1);
    col16[(size_t)pos * NTOT + d] = (unsigned short)(s & (NPER - 1));
}

// ---------------- fp32 GEMM: Z = dinv * (A @ W (+ gproj)), Z chunk-major ----------
__global__ __launch_bounds__(256) void gemm_k(const float* __restrict__ A,
                                              const float* __restrict__ W,
                                              float* __restrict__ Z,
                                              const float* __restrict__ gproj,
                                              const int* __restrict__ cnt,
                                              int K, int chunkedA) {
    __shared__ float At[32][68];
    __shared__ float Wt[32][128];
    int t = threadIdx.x;
    int row0 = blockIdx.x * 64;
    int tx = t & 31;
    int ty = t >> 5;

    float acc[8][4];
#pragma unroll
    for (int i = 0; i < 8; ++i)
#pragma unroll
        for (int j = 0; j < 4; ++j) acc[i][j] = 0.f;

    for (int kt = 0; kt < K; kt += 32) {
        {
            int r = t >> 5;
            int k = t & 31;
            int kk = kt + k;
#pragma unroll
            for (int rr = 0; rr < 8; ++rr) {
                int row = row0 + r + rr * 8;
                float val;
                if (chunkedA)
                    val = A[((size_t)(kk >> 4) * NTOT + row) * 16 + (kk & 15)];
                else
                    val = A[(size_t)row * K + kk];
                At[k][r + rr * 8] = val;
            }
        }
        {
            int c = t & 127;
            int kr = t >> 7;
#pragma unroll
            for (int kk = 0; kk < 16; ++kk)
                Wt[kr + kk * 2][c] = W[(size_t)(kt + kr + kk * 2) * 128 + c];
        }
        __syncthreads();
#pragma unroll
        for (int k = 0; k < 32; ++k) {
            float4 a0 = *(const float4*)&At[k][ty * 8];
            float4 a1 = *(const float4*)&At[k][ty * 8 + 4];
            float4 w  = *(const float4*)&Wt[k][tx * 4];
            float a[8] = {a0.x, a0.y, a0.z, a0.w, a1.x, a1.y, a1.z, a1.w};
#pragma unroll
            for (int i = 0; i < 8; ++i) {
                acc[i][0] += a[i] * w.x;
                acc[i][1] += a[i] * w.y;
                acc[i][2] += a[i] * w.z;
                acc[i][3] += a[i] * w.w;
            }
        }
        __syncthreads();
    }

    float4 g4 = make_float4(0.f, 0.f, 0.f, 0.f);
    if (gproj) {
        int g = row0 >> 10;
        g4 = *(const float4*)&gproj[(size_t)g * 128 + tx * 4];
    }
    int cc = tx >> 2;            // feature chunk
    int co = (tx & 3) * 4;       // offset within chunk
#pragma unroll
    for (int i = 0; i < 8; ++i) {
        int r = row0 + ty * 8 + i;
        float dv = rsqrtf((float)cnt[r] + 1.0f);
        float4 o;
        o.x = (acc[i][0] + g4.x) * dv;
        o.y = (acc[i][1] + g4.y) * dv;
        o.z = (acc[i][2] + g4.z) * dv;
        o.w = (acc[i][3] + g4.w) * dv;
        *(float4*)&Z[((size_t)cc * NTOT + r) * 16 + co] = o;
    }
}

// ---------------- LDS-staged GCN aggregation (weight-free inner loop) --------------
// block = (graph g, chunk c); 1024 threads, 4 lanes per node.
__global__ __launch_bounds__(1024) void agg_k(const float* __restrict__ Z,
                                              const unsigned short* __restrict__ col16,
                                              const int* __restrict__ cnt,
                                              const float* __restrict__ bias,
                                              float* __restrict__ out,
                                              float* __restrict__ lin3p,
                                              const float* __restrict__ W3,
                                              float* __restrict__ part) {
    __shared__ float4 sy4[4096];   // 64 KB
    int t = threadIdx.x;
    int g = blockIdx.x >> 3;
    int c = blockIdx.x & 7;
    int gbase = g << 10;

    const float4* Zg4 = (const float4*)(Z + ((size_t)c * NTOT + gbase) * 16);
#pragma unroll
    for (int j = 0; j < 4; ++j) sy4[j * 1024 + t] = Zg4[j * 1024 + t];
    __syncthreads();

    int f4 = t & 3;
    int vl = t >> 2;                        // 0..255
    float4 bias4 = *(const float4*)(bias + c * 16 + f4 * 4);
    float4 w34 = make_float4(0.f, 0.f, 0.f, 0.f);
    if (W3) w34 = *(const float4*)(W3 + c * 16 + f4 * 4);
    float4 vmax = make_float4(-INFINITY, -INFINITY, -INFINITY, -INFINITY);

#pragma unroll 1
    for (int pass = 0; pass < 4; ++pass) {
        int v = pass * 256 + vl;
        int gv = gbase + v;
        int n = cnt[gv];
        float dv = rsqrtf((float)n + 1.0f);
        const unsigned short* ip = col16 + gv;
        float4 acc = sy4[v * 4 + f4];       // self term (Z already dinv-scaled)
        int i = 0;
        for (; i + 2 <= n; i += 2) {
            int a = ip[(size_t)i * NTOT];
            int b = ip[(size_t)(i + 1) * NTOT];
            float4 ya = sy4[a * 4 + f4];
            float4 yb = sy4[b * 4 + f4];
            acc.x += ya.x + yb.x;
            acc.y += ya.y + yb.y;
            acc.z += ya.z + yb.z;
            acc.w += ya.w + yb.w;
        }
        if (i < n) {
            int a = ip[(size_t)i * NTOT];
            float4 ya = sy4[a * 4 + f4];
            acc.x += ya.x; acc.y += ya.y; acc.z += ya.z; acc.w += ya.w;
        }
        acc.x = fmaxf(acc.x * dv + bias4.x, 0.f);
        acc.y = fmaxf(acc.y * dv + bias4.y, 0.f);
        acc.z = fmaxf(acc.z * dv + bias4.z, 0.f);
        acc.w = fmaxf(acc.w * dv + bias4.w, 0.f);
        if (out) *(float4*)(out + ((size_t)c * NTOT + gv) * 16 + f4 * 4) = acc;
        if (W3) {   // partial dot over this chunk's 16 features
            float p = acc.x * w34.x + acc.y * w34.y + acc.z * w34.z + acc.w * w34.w;
            p += __shfl_xor(p, 1);
            p += __shfl_xor(p, 2);
            if (f4 == 0) lin3p[(size_t)c * NTOT + gv] = p;
        }
        if (part) {
            vmax.x = fmaxf(vmax.x, acc.x);
            vmax.y = fmaxf(vmax.y, acc.y);
            vmax.z = fmaxf(vmax.z, acc.z);
            vmax.w = fmaxf(vmax.w, acc.w);
        }
    }

    if (part) {   // tree-reduce max over 256 node groups, reusing sy4
        __syncthreads();
        sy4[t] = vmax;
        __syncthreads();
        for (int s = 128; s >= 1; s >>= 1) {
            if (vl < s) {
                float4 a = sy4[t], b2 = sy4[t + s * 4];
                a.x = fmaxf(a.x, b2.x); a.y = fmaxf(a.y, b2.y);
                a.z = fmaxf(a.z, b2.z); a.w = fmaxf(a.w, b2.w);
                sy4[t] = a;
            }
            __syncthreads();
        }
        if (t < 4) *(float4*)(part + (size_t)g * 128 + c * 16 + t * 4) = sy4[t];
    }
}

// ---------------- glob = maxpool@Wf + bf ; gproj = glob @ W2[128:256,:] --------------
__global__ __launch_bounds__(128) void glob_k(const float* __restrict__ part,
                                              const float* __restrict__ Wf,
                                              const float* __restrict__ bf,
                                              const float* __restrict__ W2,
                                              float* __restrict__ gproj) {
    __shared__ float mp[128];
    __shared__ float gl[128];
    int g = blockIdx.x, t = threadIdx.x;
    mp[t] = part[(size_t)g * 128 + t];
    __syncthreads();
    float acc = bf[t];
    for (int k = 0; k < 128; ++k) acc += mp[k] * Wf[(size_t)k * 128 + t];
    gl[t] = acc;
    __syncthreads();
    float acc2 = 0.f;
    for (int k = 0; k < 128; ++k) acc2 += gl[k] * W2[(size_t)(128 + k) * 128 + t];
    gproj[(size_t)g * 128 + t] = acc2;
}

// ---------------- zl[v] = dinv[v] * sum of 8 chunk partials --------------------------
__global__ __launch_bounds__(256) void lin3sum_k(const float* __restrict__ lin3p,
                                                 const int* __restrict__ cnt,
                                                 float* __restrict__ zl) {
    int v = blockIdx.x * 256 + threadIdx.x;
    float s = 0.f;
#pragma unroll
    for (int c = 0; c < NCH; ++c) s += lin3p[(size_t)c * NTOT + v];
    zl[v] = s * rsqrtf((float)cnt[v] + 1.0f);
}

// ---------------- scalar aggregation for logits --------------------------------------
__global__ __launch_bounds__(256) void sagg_k(const float* __restrict__ zl,
                                              const unsigned short* __restrict__ col16,
                                              const int* __restrict__ cnt,
                                              const float* __restrict__ b3,
                                              float* __restrict__ logits) {
    int v = blockIdx.x * 256 + threadIdx.x;
    if (v >= NTOT) return;
    int gbase = v & ~(NPER - 1);
    int n = cnt[v];
    float dv = rsqrtf((float)n + 1.0f);
    float acc = zl[v];
    const unsigned short* ip = col16 + v;
    int i = 0;
    for (; i + 2 <= n; i += 2) {
        int a = ip[(size_t)i * NTOT];
        int b = ip[(size_t)(i + 1) * NTOT];
        acc += zl[gbase + a] + zl[gbase + b];
    }
    for (; i < n; ++i) acc += zl[gbase + ip[(size_t)i * NTOT]];
    logits[v] = acc * dv + b3[0];
}

// ---------------- per-graph top-K threshold + mask -----------------------------------
__global__ __launch_bounds__(256) void mask_k(const float* __restrict__ logits,
                                              float* __restrict__ out) {
    __shared__ float sl[1024];
    __shared__ float rv[256];
    __shared__ int   ri[256];
    __shared__ float sth;
    int g = blockIdx.x, t = threadIdx.x;
    const float* lg = logits + (size_t)g * 1024;
#pragma unroll
    for (int i = 0; i < 4; ++i) sl[t + 256 * i] = lg[t + 256 * i];
    __syncthreads();
    for (int pass = 0; pass < KSEL; ++pass) {
        float bv = -INFINITY;
        int bi = 0;
#pragma unroll
        for (int i = 0; i < 4; ++i) {
            float v = sl[t + 256 * i];
            if (v > bv) { bv = v; bi = t + 256 * i; }
        }
        rv[t] = bv; ri[t] = bi;
        __syncthreads();
        for (int s = 128; s > 0; s >>= 1) {
            if (t < s) {
                if (rv[t + s] > rv[t]) { rv[t] = rv[t + s]; ri[t] = ri[t + s]; }
            }
            __syncthreads();
        }
        if (t == 0) { sth = rv[0]; sl[ri[0]] = -INFINITY; }
        __syncthreads();
    }
    float th = sth;
#pragma unroll
    for (int i = 0; i < 4; ++i) {
        float v = lg[t + 256 * i];
        out[(size_t)g * 1024 + t + 256 * i] = (v >= th) ? 1.f : 0.f;
    }
}

// =====================================================================================
extern "C" void kernel_launch(void* const* d_in, const int* in_sizes, int n_in,
                              void* d_out, int out_size, void* d_ws, size_t ws_size,
                              hipStream_t stream) {
    const float* x        = (const float*)d_in[0];
    const int*   edge_src = (const int*)d_in[1];
    const int*   edge_dst = (const int*)d_in[2];
    const float* W0 = (const float*)d_in[4];
    const float* b0 = (const float*)d_in[5];
    const float* W1 = (const float*)d_in[6];
    const float* b1 = (const float*)d_in[7];
    const float* Wf = (const float*)d_in[8];
    const float* bf = (const float*)d_in[9];
    const float* W2 = (const float*)d_in[10];
    const float* b2 = (const float*)d_in[11];
    const float* W3 = (const float*)d_in[12];
    const float* b3 = (const float*)d_in[13];
    float* out = (float*)d_out;

    char* w = (char*)d_ws;
    int*            cnt    = (int*)w;            w += (size_t)NTOT * 4;
    unsigned short* col16  = (unsigned short*)w; w += (size_t)NTOT * MAXDEG * 2;
    float*          P      = (float*)w;          w += (size_t)NTOT * 128 * 4;
    float*          Q      = (float*)w;          w += (size_t)NTOT * 128 * 4;
    float*          part   = (float*)w;          w += (size_t)NB * 128 * 4;
    float*          gproj  = (float*)w;          w += (size_t)NB * 128 * 4;
    float*          lin3p  = (float*)w;          w += (size_t)NCH * NTOT * 4;
    float*          zl     = (float*)w;          w += (size_t)NTOT * 4;
    float*          logits = (float*)w;          w += (size_t)NTOT * 4;

    hipMemsetAsync(cnt, 0, (size_t)NTOT * 4, stream);
    csr_k<<<ETOT / 256, 256, 0, stream>>>(edge_src, edge_dst, cnt, col16);

    // conv0: P = Z0 = dinv*(x@W0);  Q = h0 = relu(dinv*agg+b0); fused maxpool -> part
    gemm_k<<<NTOT / 64, 256, 0, stream>>>(x, W0, P, nullptr, cnt, FEAT, 0);
    agg_k<<<NB * NCH, 1024, 0, stream>>>(P, col16, cnt, b0, Q, nullptr, nullptr, part);

    glob_k<<<NB, 128, 0, stream>>>(part, Wf, bf, W2, gproj);

    // conv1 twice (same weights), ping-pong Q->P->Q->P->Q
    gemm_k<<<NTOT / 64, 256, 0, stream>>>(Q, W1, P, nullptr, cnt, HID, 1);
    agg_k<<<NB * NCH, 1024, 0, stream>>>(P, col16, cnt, b1, Q, nullptr, nullptr, nullptr);
    gemm_k<<<NTOT / 64, 256, 0, stream>>>(Q, W1, P, nullptr, cnt, HID, 1);
    agg_k<<<NB * NCH, 1024, 0, stream>>>(P, col16, cnt, b1, Q, nullptr, nullptr, nullptr);

    // conv2 on concat (gproj added in gemm epilogue, pre-norm); fused lin3 partials
    gemm_k<<<NTOT / 64, 256, 0, stream>>>(Q, W2, P, gproj, cnt, HID, 1);
    agg_k<<<NB * NCH, 1024, 0, stream>>>(P, col16, cnt, b2, nullptr, lin3p, W3, nullptr);

    lin3sum_k<<<NTOT / 256, 256, 0, stream>>>(lin3p, cnt, zl);
    sagg_k<<<NTOT / 256, 256, 0, stream>>>(zl, col16, cnt, b3, logits);
    mask_k<<<NB, 256, 0, stream>>>(logits, out);
}